// Round 3
// baseline (396.026 us; speedup 1.0000x reference)
//
#include <hip/hip_runtime.h>

#define D      8192
#define K      1024
#define BLOCK  256
#define GRID_MAX 2048
#define SCALE  0.011048543456039806f   // 1/sqrt(8192)
#define MAXE   8                       // max scatter entries per lane (64*8=512 >= any sane run)

typedef float nat_f4 __attribute__((ext_vector_type(4)));

// ---------------------------------------------------------------------------
// Wave-private FWHT: block = 4 waves, wave w owns orig indices [2048w, 2048w+2048)
// (bits b11,b12 = w). idx is SORTED -> wave w's scatter entries are a contiguous
// run [lo_w, hi_w) of idx/u. Phases:
//   zero region -> scatter run -> P1 (b0-4) -> P2 (b5-9)   : all wave-private,
//       same-wave LDS ops are processed in order -> NO barriers.
//   BARRIER -> P3 (b10-12, cross-wave) + store -> BARRIER  : 2 barriers/row.
// Layouts (word = f32 index, region-relative r = i & 2047):
//   L0: word = 4*swz(r>>2) + (r&3), swz(f)=f^((f>>3)&7).  scatter writes, P1 reads
//       (P1: lane l reads f4 8l+(g^(l&7)) -> 8 lanes/bank-quad = b128 structural min)
//   L1: word = (j<<6)|l_old (j=b0..4, l_old=b5..10), same swz.  P1 writes
//       (per-j: 2x32 contiguous words -> 2 lanes/bank), P2 reads (8/quad min).
//   L2: word = (h<<10)|(T'<<2)|s,  h=(b10,b11,b12), T'=(b2b3b4)|(b5..b9)<<3,
//       s=(b0,b1).  P2 writes contiguous-32 (2/bank), P3 reads contiguous f4
//       (2/bank) -- no swizzle needed.  P3 store: identical formula to prior kernel.
// ---------------------------------------------------------------------------

__device__ __forceinline__ void fwht32(float* x) {
#pragma unroll
    for (int s = 0; s < 5; ++s) {
        const int h = 1 << s;
#pragma unroll
        for (int g = 0; g < 32; g += 2 * h)
#pragma unroll
            for (int e = 0; e < h; ++e) {
                float a = x[g + e], b = x[g + e + h];
                x[g + e]     = a + b;
                x[g + e + h] = a - b;
            }
    }
}

__device__ __forceinline__ void fwht8(float* x) {
#pragma unroll
    for (int s = 0; s < 3; ++s) {
        const int h = 1 << s;
#pragma unroll
        for (int g = 0; g < 8; g += 2 * h)
#pragma unroll
            for (int e = 0; e < h; ++e) {
                float a = x[g + e], b = x[g + e + h];
                x[g + e]     = a + b;
                x[g + e + h] = a - b;
            }
    }
}

__global__ __launch_bounds__(BLOCK, 5)
void UpProjectFastHadamardTransform_80101140070867_kernel(
    const float* __restrict__ u, const int* __restrict__ idx,
    float* __restrict__ out, int nrows)
{
    __shared__ float4 lds4[D / 4];
    float* lds = (float*)lds4;
    const int T = threadIdx.x;
    const int w = T >> 6;          // wave id (= b11,b12)
    const int l = T & 63;          // lane

    // ---- prologue (once per block; idx is fixed across rows) ----
    // run boundaries: lo = #{idx < 2048w}, hi = #{idx < 2048(w+1)}
    int clo = 0, chi = 0;
    const int rlo = w << 11, rhi = rlo + 2048;
#pragma unroll
    for (int s = 0; s < 16; ++s) {
        const int v = idx[l + 64 * s];
        clo += (v < rlo);
        chi += (v < rhi);
    }
#pragma unroll
    for (int d = 32; d; d >>= 1) {
        clo += __shfl_xor(clo, d, 64);
        chi += __shfl_xor(chi, d, 64);
    }
    const int lo = clo, hi = chi;
    const int Jw = (hi - lo + 63) >> 6;      // wave-uniform entry count per lane

    // per-lane scatter addresses (phys, region-relative words), fixed across rows
    int aj[MAXE];
#pragma unroll
    for (int j = 0; j < MAXE; ++j) {
        const int k = lo + l + (j << 6);
        int a = -1;
        if (j < Jw && k < hi) {
            const int r = idx[k] & 2047;
            const int f = r >> 2;
            a = 4 * (f ^ ((f >> 3) & 7)) + (r & 3);
        }
        aj[j] = a;
    }

    // address helpers
    const int ldsW   = w << 11;                              // region word base
    const int lds4W  = w << 9;                               // region f4 base
    const int c1     = l & 7;                                // P1 read xor
    const int c2     = ((l << 1) + (l >> 5)) & 7;            // P2 read xor
    const int p1_lo2 = l >> 2, p1_hi = l >> 5, p1_e = l & 3; // P1 write pieces
    const int p2r_b4 = ((l & 31) << 4) + ((l >> 5) << 3);    // P2 read f4 base
    const int p2w_b  = ((((l >> 5) | (w << 1)) << 10) |      // P2 write word base
                        (((l >> 2) & 7) << 2) | (l & 3));

    int r = blockIdx.x;
    const int stride = (int)gridDim.x;

    // first row's u values
    float vc[MAXE], vn[MAXE];
    {
        const float* ur = u + (size_t)r * K;
#pragma unroll
        for (int j = 0; j < MAXE; ++j)
            vc[j] = (aj[j] >= 0) ? ur[lo + l + (j << 6)] : 0.f;
    }

    while (r < nrows) {
        __syncthreads();                     // prev-row P3 cross-region reads done

        // zero own region (wave-private, contiguous b128)
#pragma unroll
        for (int q = 0; q < 8; ++q)
            lds4[lds4W + (q << 6) + l] = make_float4(0.f, 0.f, 0.f, 0.f);

        // scatter own run (wave-private; same-wave LDS ops are in-order)
#pragma unroll
        for (int j = 0; j < MAXE; ++j)
            if (aj[j] >= 0) atomicAdd(&lds[ldsW + aj[j]], vc[j]);
        if (Jw > MAXE) {                     // correctness fallback, ~never taken
            const float* ur = u + (size_t)r * K;
            for (int k = lo + l + (MAXE << 6); k < hi; k += 64) {
                const int rr = idx[k] & 2047;
                const int f  = rr >> 2;
                atomicAdd(&lds[ldsW + 4 * (f ^ ((f >> 3) & 7)) + (rr & 3)], ur[k]);
            }
        }

        // prefetch next row's u (hidden under P1/P2)
        const int rn = r + stride;
        if (rn < nrows) {
            const float* ur = u + (size_t)rn * K;
#pragma unroll
            for (int j = 0; j < MAXE; ++j)
                vn[j] = (aj[j] >= 0) ? ur[lo + l + (j << 6)] : 0.f;
        }

        float x[32];

        // ---- P1: bits 0-4 (wave-private) ----
#pragma unroll
        for (int g = 0; g < 8; ++g) {
            const float4 a = lds4[lds4W + (l << 3) + (g ^ c1)];
            x[4*g+0] = a.x; x[4*g+1] = a.y; x[4*g+2] = a.z; x[4*g+3] = a.w;
        }
        fwht32(x);
#pragma unroll
        for (int j = 0; j < 32; ++j) {       // transposed write -> L1 (swizzled)
            const int f = (j << 4) + p1_lo2;
            lds[ldsW + 4 * (f ^ ((2 * j + p1_hi) & 7)) + p1_e] = x[j];
        }

        // ---- P2: bits 5-9 (wave-private) ----
#pragma unroll
        for (int g = 0; g < 8; ++g) {
            const float4 a = lds4[lds4W + p2r_b4 + (g ^ c2)];
            x[4*g+0] = a.x; x[4*g+1] = a.y; x[4*g+2] = a.z; x[4*g+3] = a.w;
        }
        fwht32(x);
#pragma unroll
        for (int m = 0; m < 32; ++m)         // -> L2 (contiguous-32 per instr)
            lds[p2w_b + (m << 5)] = x[m];

        __syncthreads();                     // all waves' L2 ready

        // ---- P3: bits 10-12 (cross-wave) + store ----
#pragma unroll
        for (int h = 0; h < 8; ++h) {
            const float4 a = lds4[(h << 8) + T];
            x[h] = a.x; x[8 + h] = a.y; x[16 + h] = a.z; x[24 + h] = a.w;
        }
#pragma unroll
        for (int q = 0; q < 4; ++q) fwht8(&x[q * 8]);

        float* orow = out + (size_t)r * D + ((T >> 3) * 32 + (T & 7) * 4);
#pragma unroll
        for (int e = 0; e < 8; ++e) {
            nat_f4 o = { x[e] * SCALE, x[8 + e] * SCALE,
                         x[16 + e] * SCALE, x[24 + e] * SCALE };
            __builtin_nontemporal_store(o, (nat_f4*)(orow + e * 1024));
        }

        // rotate prefetched u
#pragma unroll
        for (int j = 0; j < MAXE; ++j) vc[j] = vn[j];
        r = rn;
    }
}

extern "C" void kernel_launch(void* const* d_in, const int* in_sizes, int n_in,
                              void* d_out, int out_size, void* d_ws, size_t ws_size,
                              hipStream_t stream) {
    const float* u   = (const float*)d_in[0];
    const int*   idx = (const int*)d_in[1];
    float*       out = (float*)d_out;
    const int rows = in_sizes[0] / K;   // 8192
    const int grid = rows < GRID_MAX ? rows : GRID_MAX;
    hipLaunchKernelGGL(UpProjectFastHadamardTransform_80101140070867_kernel,
                       dim3(grid), dim3(BLOCK), 0, stream, u, idx, out, rows);
}

// Round 4
// 358.337 us; speedup vs baseline: 1.1052x; 1.1052x over previous
//
#include <hip/hip_runtime.h>

#define D      8192
#define K      1024
#define BLOCK  256
#define GRID_MAX 2048
#define SCALE  0.011048543456039806f   // 1/sqrt(8192)

typedef float nat_f4 __attribute__((ext_vector_type(4)));

// ---------------------------------------------------------------------------
// Hybrid: round-0 scatter (register-light) + wave-private P1/P2 (barrier-light).
// Block = 4 waves; wave w owns orig indices [2048w, 2048w+2048) (bits b11,b12=w).
// Per row: zero (all) -> BAR -> scatter (all, 4 atomics/thread) -> BAR ->
//          P1 (b0-4) + P2 (b5-9) wave-private, NO barrier between ->
//          BAR -> P3 (b10-12, cross-wave) + store -> BAR(top of loop).
// 4 barriers/row (vs 6 in round 0). No per-row register arrays beyond x[32]
// (round-3's aj/vc/vn spilled to scratch: 100 MB extra FETCH+WRITE, +39 us).
//
// Layouts (verified exact-match in round 3; global swz4 == region-local swz4
// + region base since region bits b11,b12 don't reach the xor field):
//   L0: word = 4*swz4(i>>2) + (i&3), swz4(f)=f^((f>>3)&7).
//   P1 read:  lane reads f4 (T<<3)+(g^(T&7))  -> 8 lanes/bank-quad (b128 min).
//   L1 write: f=(j<<4)+(l>>2): word = ldsW + 4*(f^((2j+(l>>5))&7)) + (l&3)
//             -> 64 consecutive swizzled words, 2 lanes/bank.
//   P2 read:  f4 = lds4W + ((l&31)<<4) + ((l>>5)<<3) + (g^c2), c2=(2l+(l>>5))&7.
//   L2 write: word = ((2w|(l>>5))<<10) | (m<<5) | (((l>>2)&7)<<2) | (l&3)
//             -> contiguous-32 per m, 2 lanes/bank.  (own region: h=2w|..)
//   P3 read:  f4 = (h<<8)+T, contiguous b128.  Store: same formula as always.
// ---------------------------------------------------------------------------

__device__ __forceinline__ int swz4(int f) { return f ^ ((f >> 3) & 7); }

__device__ __forceinline__ void fwht32(float* x) {
#pragma unroll
    for (int s = 0; s < 5; ++s) {
        const int h = 1 << s;
#pragma unroll
        for (int g = 0; g < 32; g += 2 * h)
#pragma unroll
            for (int e = 0; e < h; ++e) {
                float a = x[g + e], b = x[g + e + h];
                x[g + e]     = a + b;
                x[g + e + h] = a - b;
            }
    }
}

__device__ __forceinline__ void fwht8(float* x) {
#pragma unroll
    for (int s = 0; s < 3; ++s) {
        const int h = 1 << s;
#pragma unroll
        for (int g = 0; g < 8; g += 2 * h)
#pragma unroll
            for (int e = 0; e < h; ++e) {
                float a = x[g + e], b = x[g + e + h];
                x[g + e]     = a + b;
                x[g + e + h] = a - b;
            }
    }
}

__global__ __launch_bounds__(BLOCK, 5)
void UpProjectFastHadamardTransform_80101140070867_kernel(
    const float* __restrict__ u, const int* __restrict__ idx,
    float* __restrict__ out, int nrows)
{
    __shared__ float4 lds4[D / 4];
    float* lds = (float*)lds4;
    const int T = threadIdx.x;
    const int w = T >> 6;          // wave id (= b11,b12)
    const int l = T & 63;          // lane

    const int4 id = ((const int4*)idx)[T];   // once per block; 4 regs held

    // address helpers (cheap scalars, recomputed-free)
    const int ldsW   = w << 11;                              // region word base
    const int lds4W  = w << 9;                               // region f4 base
    const int c1     = T & 7;                                // P1 read xor
    const int c2     = ((l << 1) + (l >> 5)) & 7;            // P2 read xor
    const int p1_lo2 = l >> 2, p1_hi = l >> 5, p1_e = l & 3; // P1 write pieces
    const int p2r_b4 = ((l & 31) << 4) + ((l >> 5) << 3);    // P2 read f4 base
    const int p2w_b  = ((((l >> 5) | (w << 1)) << 10) |      // P2 write word base
                        (((l >> 2) & 7) << 2) | (l & 3));

    int r = blockIdx.x;
    const int stride = (int)gridDim.x;
    float4 v = ((const float4*)(u + (size_t)r * K))[T];      // current row's u

    while (r < nrows) {
        __syncthreads();                     // prev-row P3 cross-region reads done

        // zero LDS (block-wide, contiguous b128)
#pragma unroll
        for (int q = 0; q < 8; ++q)
            lds4[(q << 8) + T] = make_float4(0.f, 0.f, 0.f, 0.f);
        __syncthreads();

        // scatter-add (cross-wave, duplicate idx accumulate)
        {
            int f, a;
            f = id.x >> 2; a = 4 * swz4(f) + (id.x & 3); atomicAdd(&lds[a], v.x);
            f = id.y >> 2; a = 4 * swz4(f) + (id.y & 3); atomicAdd(&lds[a], v.y);
            f = id.z >> 2; a = 4 * swz4(f) + (id.z & 3); atomicAdd(&lds[a], v.z);
            f = id.w >> 2; a = 4 * swz4(f) + (id.w & 3); atomicAdd(&lds[a], v.w);
        }

        // prefetch next row's u (single float4 — 4 regs, no spill pressure)
        const int rn = r + stride;
        if (rn < nrows) v = ((const float4*)(u + (size_t)rn * K))[T];
        __syncthreads();                     // L0 complete

        float x[32];

        // ---- P1: bits 0-4 (wave-private from here) ----
#pragma unroll
        for (int g = 0; g < 8; ++g) {
            const float4 a = lds4[(T << 3) + (g ^ c1)];
            x[4*g+0] = a.x; x[4*g+1] = a.y; x[4*g+2] = a.z; x[4*g+3] = a.w;
        }
        fwht32(x);
#pragma unroll
        for (int j = 0; j < 32; ++j) {       // transposed write -> L1 (swizzled)
            const int f = (j << 4) + p1_lo2;
            lds[ldsW + 4 * (f ^ ((2 * j + p1_hi) & 7)) + p1_e] = x[j];
        }

        // ---- P2: bits 5-9 (same wave read-own-writes; LDS ops in-order) ----
#pragma unroll
        for (int g = 0; g < 8; ++g) {
            const float4 a = lds4[lds4W + p2r_b4 + (g ^ c2)];
            x[4*g+0] = a.x; x[4*g+1] = a.y; x[4*g+2] = a.z; x[4*g+3] = a.w;
        }
        fwht32(x);
#pragma unroll
        for (int m = 0; m < 32; ++m)         // -> L2 (contiguous-32 per instr)
            lds[p2w_b + (m << 5)] = x[m];

        __syncthreads();                     // all waves' L2 ready

        // ---- P3: bits 10-12 (cross-wave) + store ----
#pragma unroll
        for (int h = 0; h < 8; ++h) {
            const float4 a = lds4[(h << 8) + T];
            x[h] = a.x; x[8 + h] = a.y; x[16 + h] = a.z; x[24 + h] = a.w;
        }
#pragma unroll
        for (int q = 0; q < 4; ++q) fwht8(&x[q * 8]);

        float* orow = out + (size_t)r * D + ((T >> 3) * 32 + (T & 7) * 4);
#pragma unroll
        for (int e = 0; e < 8; ++e) {
            nat_f4 o = { x[e] * SCALE, x[8 + e] * SCALE,
                         x[16 + e] * SCALE, x[24 + e] * SCALE };
            __builtin_nontemporal_store(o, (nat_f4*)(orow + e * 1024));
        }

        r = rn;
    }
}

extern "C" void kernel_launch(void* const* d_in, const int* in_sizes, int n_in,
                              void* d_out, int out_size, void* d_ws, size_t ws_size,
                              hipStream_t stream) {
    const float* u   = (const float*)d_in[0];
    const int*   idx = (const int*)d_in[1];
    float*       out = (float*)d_out;
    const int rows = in_sizes[0] / K;   // 8192
    const int grid = rows < GRID_MAX ? rows : GRID_MAX;
    hipLaunchKernelGGL(UpProjectFastHadamardTransform_80101140070867_kernel,
                       dim3(grid), dim3(BLOCK), 0, stream, u, idx, out, rows);
}